// Round 3
// baseline (237.654 us; speedup 1.0000x reference)
//
#include <hip/hip_runtime.h>

#define BATCH 32
#define NAG   4096
#define FDIM  128
#define LREC  200      // L*DH floats per (b,n) record in hist_feat
#define KSEL  8

// ---------------------------------------------------------------------------
// Kernel 1: one wave handles EIGHT agents. Lane layout: group g = lane>>3
// owns agent n0+g; sub = lane&7 indexes 4 float4 chunks (8 lanes x 16B =
// one 128B line per group per chunk). Butterfly within 8-lane groups
// (masks 4/2/1), then a 4-shuffle redistribution puts agent g's sums on
// lane g so the sqrt/div-heavy epilogue runs LANE-PARALLEL (8 agents at
// once) instead of exec-masked to 1-2 lanes.
// scores[b*4096 + n]; slot n==0 forced to +inf.
// ---------------------------------------------------------------------------
__global__ __launch_bounds__(256) void score_kernel(
    const float* __restrict__ x,     // (B, N, FDIM)
    const float* __restrict__ hf,    // (B, N, L, DH)
    const float* __restrict__ he,    // (B, N, FDIM)
    float* __restrict__ scores)      // (B, N)
{
    const int tid  = threadIdx.x;
    const int wave = (blockIdx.x * 256 + tid) >> 6;   // 16384 waves total
    const int lane = tid & 63;
    const int g    = lane >> 3;      // which of 8 agents
    const int sub  = lane & 7;       // chunk lane within agent

    const int b  = wave >> 9;        // 512 waves per batch
    const int n0 = (wave & 511) << 3;
    const int n  = n0 + g;

    const float* xn = x  + ((size_t)(b << 12) + n) * FDIM;
    const float* xc = x  + ((size_t)(b << 12)) * FDIM;
    const float* en = he + ((size_t)(b << 12) + n) * FDIM;
    const float* ec = he + ((size_t)(b << 12)) * FDIM;

    float dist2 = 0.f, dotv = 0.f, nn = 0.f, cc = 0.f;
    #pragma unroll
    for (int t = 0; t < 4; ++t) {
        const int d = t * 32 + sub * 4;
        const float4 a = *(const float4*)(xn + d);
        const float4 c = *(const float4*)(xc + d);
        const float4 e = *(const float4*)(en + d);
        const float4 f = *(const float4*)(ec + d);
        float dx;
        dx = a.x - c.x; dist2 += dx * dx;
        dx = a.y - c.y; dist2 += dx * dx;
        dx = a.z - c.z; dist2 += dx * dx;
        dx = a.w - c.w; dist2 += dx * dx;
        dotv += e.x * f.x + e.y * f.y + e.z * f.z + e.w * f.w;
        nn   += e.x * e.x + e.y * e.y + e.z * e.z + e.w * e.w;
        cc   += f.x * f.x + f.y * f.y + f.z * f.z + f.w * f.w;
    }

    #pragma unroll
    for (int m = 4; m; m >>= 1) {     // reduce within each 8-lane group
        dist2 += __shfl_xor(dist2, m, 64);
        dotv  += __shfl_xor(dotv,  m, 64);
        nn    += __shfl_xor(nn,    m, 64);
        cc    += __shfl_xor(cc,    m, 64);
    }

    // lane L <- group L's sums (held on lane 8*L)
    const int src = (lane << 3) & 63;
    dist2 = __shfl(dist2, src, 64);
    dotv  = __shfl(dotv,  src, 64);
    nn    = __shfl(nn,    src, 64);
    cc    = __shfl(cc,    src, 64);

    if (lane < 8) {
        const int ag = n0 + lane;     // this lane's agent
        const float dist = sqrtf(dist2);
        const float traj = dotv / (fmaxf(sqrtf(nn), 1e-8f) * fmaxf(sqrtf(cc), 1e-8f));

        // velocity cosine from hist_feat[..., 48:50, 0:2]
        const float* hn = hf + ((size_t)(b << 12) + ag) * LREC + 192;
        const float* h0 = hf + ((size_t)(b << 12)) * LREC + 192;
        const float2 hn0 = *(const float2*)(hn);
        const float2 hn1 = *(const float2*)(hn + 4);
        const float2 h00 = *(const float2*)(h0);
        const float2 h01 = *(const float2*)(h0 + 4);
        const float dnx = hn1.x - hn0.x, dny = hn1.y - hn0.y;
        const float d0x = h01.x - h00.x, d0y = h01.y - h00.y;

        const float n0v = fmaxf(sqrtf(d0x * d0x + d0y * d0y), 1e-12f);
        const float cdx = d0x / n0v + 1e-8f, cdy = d0y / n0v + 1e-8f;
        const float nn2 = fmaxf(sqrtf(dnx * dnx + dny * dny), 1e-12f);
        const float odx = dnx / nn2 + 1e-8f, ody = dny / nn2 + 1e-8f;

        const float num = odx * cdx + ody * cdy;
        const float den = fmaxf(sqrtf(odx * odx + ody * ody), 1e-8f) *
                          fmaxf(sqrtf(cdx * cdx + cdy * cdy), 1e-8f);
        const float vel = num / den;

        const float score = 0.3f * dist
                          + 0.5f * (1.0f - fmaxf(vel,  0.0f))
                          + 0.4f * (1.0f - fmaxf(traj, 0.0f));
        scores[(size_t)(b << 12) + ag] = (ag == 0) ? 1e30f : score;
    }
}

// ---------------------------------------------------------------------------
// Kernel 2: one block per batch. Scores cached in 16 registers/thread;
// 8 rounds of iterative arg-min (tie-break lower index = jax.lax.top_k),
// then gather rows + write indices (as float).
// ---------------------------------------------------------------------------
__global__ __launch_bounds__(256) void topk_gather_kernel(
    const float* __restrict__ scores,
    const float* __restrict__ x,
    float* __restrict__ out)
{
    const int b   = blockIdx.x;
    const int tid = threadIdx.x;

    float v[16];
    #pragma unroll
    for (int j = 0; j < 16; ++j)
        v[j] = scores[(size_t)(b << 12) + (j << 8) + tid];  // i = j*256 + tid

    __shared__ float red_s[4];
    __shared__ int   red_i[4];
    __shared__ int   sel[KSEL];

    for (int r = 0; r < KSEL; ++r) {
        float best = 1e30f;
        int   bi   = 0x7fffffff;
        #pragma unroll
        for (int j = 0; j < 16; ++j) {
            const int   i  = (j << 8) + tid;
            const float vv = v[j];
            if (vv < best || (vv == best && i < bi)) { best = vv; bi = i; }
        }
        #pragma unroll
        for (int m = 32; m; m >>= 1) {
            const float ov = __shfl_xor(best, m, 64);
            const int   oi = __shfl_xor(bi,   m, 64);
            if (ov < best || (ov == best && oi < bi)) { best = ov; bi = oi; }
        }
        if ((tid & 63) == 0) { red_s[tid >> 6] = best; red_i[tid >> 6] = bi; }
        __syncthreads();
        if (tid == 0) {
            float bb = red_s[0]; int ii = red_i[0];
            #pragma unroll
            for (int w = 1; w < 4; ++w)
                if (red_s[w] < bb || (red_s[w] == bb && red_i[w] < ii)) {
                    bb = red_s[w]; ii = red_i[w];
                }
            sel[r] = ii;
        }
        __syncthreads();
        const int w = sel[r];
        if ((w & 255) == tid) v[w >> 8] = 1e30f;   // exclude winner locally
    }

    // gather 8 rows x 128 floats
    for (int e2 = tid; e2 < KSEL * FDIM; e2 += 256) {
        const int j = e2 >> 7;
        const int d = e2 & 127;
        const int n = sel[j];
        out[((size_t)b * KSEL + j) * FDIM + d] = x[((size_t)(b << 12) + n) * FDIM + d];
    }
    if (tid < KSEL)
        out[(size_t)BATCH * KSEL * FDIM + b * KSEL + tid] = (float)(sel[tid] - 1);
}

extern "C" void kernel_launch(void* const* d_in, const int* in_sizes, int n_in,
                              void* d_out, int out_size, void* d_ws, size_t ws_size,
                              hipStream_t stream) {
    const float* x  = (const float*)d_in[0];   // (B, N, FDIM)
    const float* hf = (const float*)d_in[1];   // (B, N, L, DH)
    const float* he = (const float*)d_in[2];   // (B, N, FDIM)
    float* out = (float*)d_out;
    float* scores = (float*)d_ws;              // B*N floats = 512 KB

    // Phase 1: 32 batches x 512 agent-octets = 16384 waves, 4 waves/block
    const int blocks1 = (BATCH * (NAG / 8) * 64) / 256;   // 4096
    score_kernel<<<blocks1, 256, 0, stream>>>(x, hf, he, scores);

    // Phase 2: one block per batch
    topk_gather_kernel<<<BATCH, 256, 0, stream>>>(scores, x, out);
}